// Round 1
// baseline (5318.190 us; speedup 1.0000x reference)
//
#include <hip/hip_runtime.h>

// Fused 2-layer LSTM, bf16 MFMA recurrence, weights resident in VGPRs.
// 16 blocks x 512 threads; block b owns batches [16b, 16b+16).
// Per wave w (8 waves): gate-row tiles {q*8+w}, q=0..3 => i/f/g/o rows of
// h-columns [w*16, w*16+16) -> elementwise is lane-local on MFMA D-frags.

typedef short bf16x8 __attribute__((ext_vector_type(8)));
typedef float f32x4 __attribute__((ext_vector_type(4)));

static constexpr int CIN = 12, T = 2048, H = 128, G = 512;
static constexpr int BPB = 16, NTHR = 512, NBLK = 16;
static constexpr float L2E = 1.4426950408889634f;

// LDS byte map
static constexpr int LDS_H0  = 0;      // 2 x 4096  (h0 double buffer, B-frag layout)
static constexpr int LDS_H1  = 8192;   // 2 x 4096  (h1 double buffer)
static constexpr int LDS_X   = 16384;  // 2 x 1024  (x_t as K=32-padded B-frag rows)
static constexpr int LDS_B0  = 18432;  // 512 f32 pre-scaled bias layer0
static constexpr int LDS_B1  = 20480;  // 512 f32 pre-scaled bias layer1
static constexpr int LDS_RED = 22528;  // 512 f32 reduction scratch (epilogue)
static constexpr int LDS_SZ  = 24576;

__device__ __forceinline__ unsigned f2bf(float f) {  // f32 -> bf16 bits, RTNE
  unsigned u = __builtin_bit_cast(unsigned, f);
  return (u + 0x7FFFu + ((u >> 16) & 1u)) >> 16;
}

__device__ __forceinline__ float sig_pre(float a) {  // 1/(1+2^a)
  return __builtin_amdgcn_rcpf(1.f + exp2f(a));
}

__global__ __launch_bounds__(NTHR, 2) void lstm_fused(
    const float* __restrict__ xg,
    const float* __restrict__ Wih0, const float* __restrict__ Whh0,
    const float* __restrict__ bih0, const float* __restrict__ bhh0,
    const float* __restrict__ Wih1, const float* __restrict__ Whh1,
    const float* __restrict__ bih1, const float* __restrict__ bhh1,
    const float* __restrict__ Wd,   const float* __restrict__ bd,
    float* __restrict__ out)
{
  __shared__ char lds[LDS_SZ];
  const int tid = threadIdx.x;
  const int l  = tid & 63;
  const int w  = tid >> 6;   // wave 0..7
  const int lg = l >> 4;     // lane group 0..3 (k-chunk)
  const int lr = l & 15;     // A: row-in-tile ; B/D: batch column
  const int b0 = blockIdx.x * BPB;

  // ---- zero LDS (x pad region + initial h0/h1 state = 0) ----
  for (int i = tid; i < LDS_SZ / 4; i += NTHR) ((int*)lds)[i] = 0;
  __syncthreads();

  // ---- load weight A-fragments (pre-scaled: i,f,o rows *-log2e ; g rows *2log2e) ----
  // A-frag: lane holds W[tile_row = lr][k = lg*8 + j], j=0..7, per (tile q, kfrag).
  bf16x8 A0[4][5];  // layer0: K = [h0(128) ; x(12 pad 32)] -> 5 kfrags
  bf16x8 A1[4][8];  // layer1: K = [h1(128) ; h0(128)]     -> 8 kfrags
  #pragma unroll
  for (int q = 0; q < 4; ++q) {
    const int n = (q * 8 + w) * 16 + lr;         // global gate row 0..511
    const float s = (q == 2) ? (2.f * L2E) : (-L2E);
    #pragma unroll
    for (int kf = 0; kf < 4; ++kf) {
      const float* src = &Whh0[n * H + kf * 32 + lg * 8];
      #pragma unroll
      for (int j = 0; j < 8; ++j) A0[q][kf][j] = (short)f2bf(src[j] * s);
    }
    #pragma unroll
    for (int j = 0; j < 8; ++j) {
      const int k = lg * 8 + j;
      A0[q][4][j] = (short)(k < CIN ? f2bf(Wih0[n * CIN + k] * s) : 0u);
    }
    #pragma unroll
    for (int kf = 0; kf < 4; ++kf) {
      const float* srcA = &Whh1[n * H + kf * 32 + lg * 8];
      const float* srcB = &Wih1[n * H + kf * 32 + lg * 8];
      #pragma unroll
      for (int j = 0; j < 8; ++j) {
        A1[q][kf][j]     = (short)f2bf(srcA[j] * s);
        A1[q][4 + kf][j] = (short)f2bf(srcB[j] * s);
      }
    }
  }

  if (tid < G) {
    const float s = ((tid >> 7) == 2) ? (2.f * L2E) : (-L2E);
    ((float*)(lds + LDS_B0))[tid] = (bih0[tid] + bhh0[tid]) * s;
    ((float*)(lds + LDS_B1))[tid] = (bih1[tid] + bhh1[tid]) * s;
  }

  // per-lane LDS addresses
  const int rdB  = lg * 256 + lr * 16;                       // B-frag read base
  const int bcol = w * 16 + lg * 4;                          // base h-column (4 per lane)
  const int wrH  = (bcol >> 3) * 256 + lr * 16 + (bcol & 7) * 2;
  const int xb = tid & 15, xc = tid >> 4;                    // x loader role (tid<192)
  const int wrX = (xc >> 3) * 256 + xb * 16 + (xc & 7) * 2;
  const size_t xbase = (size_t)(b0 + xb) * (CIN * T) + (size_t)xc * T;

  // x(t=0) into X[0]
  if (tid < 192)
    *(unsigned short*)(lds + LDS_X + wrX) = (unsigned short)f2bf(xg[xbase]);
  __syncthreads();

  float c0v[4] = {0.f, 0.f, 0.f, 0.f};
  float c1v[4] = {0.f, 0.f, 0.f, 0.f};
  float h1v[4] = {0.f, 0.f, 0.f, 0.f};

  #pragma unroll 1
  for (int t = 0; t < T; ++t) {
    const int p = t & 1;
    // prefetch x(t+1) (consumed late in this iteration)
    float xnext = 0.f;
    if (tid < 192) xnext = xg[xbase + (t + 1 < T ? t + 1 : t)];

    // ================= layer 0 =================
    f32x4 acc[4];
    #pragma unroll
    for (int q = 0; q < 4; ++q)
      acc[q] = *(const f32x4*)(lds + LDS_B0 + (q * 8 + w) * 64 + lg * 16);
    #pragma unroll
    for (int kf = 0; kf < 5; ++kf) {
      const int src = (kf < 4) ? (LDS_H0 + p * 4096 + kf * 1024 + rdB)
                               : (LDS_X + p * 1024 + rdB);
      const bf16x8 bf = *(const bf16x8*)(lds + src);
      #pragma unroll
      for (int q = 0; q < 4; ++q)
        acc[q] = __builtin_amdgcn_mfma_f32_16x16x32_bf16(A0[q][kf], bf, acc[q], 0, 0, 0);
    }
    {
      unsigned hp0 = 0, hp1 = 0;
      #pragma unroll
      for (int r = 0; r < 4; ++r) {
        const float iv = sig_pre(acc[0][r]);
        const float fv = sig_pre(acc[1][r]);
        const float gv = 1.f - 2.f * sig_pre(acc[2][r]);
        const float ov = sig_pre(acc[3][r]);
        const float c  = fmaf(fv, c0v[r], iv * gv);
        c0v[r] = c;
        const float th = 1.f - 2.f * sig_pre(c * (2.f * L2E));
        const unsigned hb = f2bf(ov * th);
        if (r == 0) hp0 = hb; else if (r == 1) hp0 |= hb << 16;
        else if (r == 2) hp1 = hb; else hp1 |= hb << 16;
      }
      const unsigned long long hv = ((unsigned long long)hp1 << 32) | hp0;
      *(unsigned long long*)(lds + LDS_H0 + (1 - p) * 4096 + wrH) = hv;
    }
    if (tid < 192)
      *(unsigned short*)(lds + LDS_X + (1 - p) * 1024 + wrX) =
          (unsigned short)f2bf(xnext);
    __syncthreads();

    // ================= layer 1 =================
    #pragma unroll
    for (int q = 0; q < 4; ++q)
      acc[q] = *(const f32x4*)(lds + LDS_B1 + (q * 8 + w) * 64 + lg * 16);
    #pragma unroll
    for (int kf = 0; kf < 8; ++kf) {
      const int src = (kf < 4)
          ? (LDS_H1 + p * 4096 + kf * 1024 + rdB)
          : (LDS_H0 + (1 - p) * 4096 + (kf - 4) * 1024 + rdB);  // h0(t) just written
      const bf16x8 bf = *(const bf16x8*)(lds + src);
      #pragma unroll
      for (int q = 0; q < 4; ++q)
        acc[q] = __builtin_amdgcn_mfma_f32_16x16x32_bf16(A1[q][kf], bf, acc[q], 0, 0, 0);
    }
    {
      unsigned hp0 = 0, hp1 = 0;
      #pragma unroll
      for (int r = 0; r < 4; ++r) {
        const float iv = sig_pre(acc[0][r]);
        const float fv = sig_pre(acc[1][r]);
        const float gv = 1.f - 2.f * sig_pre(acc[2][r]);
        const float ov = sig_pre(acc[3][r]);
        const float c  = fmaf(fv, c1v[r], iv * gv);
        c1v[r] = c;
        const float th = 1.f - 2.f * sig_pre(c * (2.f * L2E));
        h1v[r] = ov * th;
        const unsigned hb = f2bf(h1v[r]);
        if (r == 0) hp0 = hb; else if (r == 1) hp0 |= hb << 16;
        else if (r == 2) hp1 = hb; else hp1 |= hb << 16;
      }
      const unsigned long long hv = ((unsigned long long)hp1 << 32) | hp0;
      *(unsigned long long*)(lds + LDS_H1 + (1 - p) * 4096 + wrH) = hv;
    }
    __syncthreads();
  }

  // ---- epilogue: feats = h1(T-1) (f32 from regs), scores = sigmoid(h1.Wd + bd) ----
  const float4 wd = *(const float4*)&Wd[bcol];
  const float partial = h1v[0] * wd.x + h1v[1] * wd.y + h1v[2] * wd.z + h1v[3] * wd.w;
  #pragma unroll
  for (int r = 0; r < 4; ++r)
    out[256 + (size_t)(b0 + lr) * H + (bcol + r)] = h1v[r];
  ((float*)(lds + LDS_RED))[tid] = partial;
  __syncthreads();
  if (tid < 16) {
    float s = 0.f;
    #pragma unroll 8
    for (int k = 0; k < 32; ++k) s += ((float*)(lds + LDS_RED))[tid + 16 * k];
    const float v = s + bd[0];
    out[b0 + tid] = __builtin_amdgcn_rcpf(1.f + exp2f(-v * L2E));
  }
}

extern "C" void kernel_launch(void* const* d_in, const int* in_sizes, int n_in,
                              void* d_out, int out_size, void* d_ws, size_t ws_size,
                              hipStream_t stream) {
  const float* x    = (const float*)d_in[0];
  // d_in[1] = seq_lengths : unused by the reference
  const float* Wih0 = (const float*)d_in[2];
  const float* Whh0 = (const float*)d_in[3];
  const float* bih0 = (const float*)d_in[4];
  const float* bhh0 = (const float*)d_in[5];
  const float* Wih1 = (const float*)d_in[6];
  const float* Whh1 = (const float*)d_in[7];
  const float* bih1 = (const float*)d_in[8];
  const float* bhh1 = (const float*)d_in[9];
  const float* Wd   = (const float*)d_in[10];
  const float* bd   = (const float*)d_in[11];
  (void)in_sizes; (void)n_in; (void)out_size; (void)d_ws; (void)ws_size;

  lstm_fused<<<dim3(NBLK), dim3(NTHR), 0, stream>>>(
      x, Wih0, Whh0, bih0, bhh0, Wih1, Whh1, bih1, bhh1, Wd, bd, (float*)d_out);
}

// Round 2
// 5245.157 us; speedup vs baseline: 1.0139x; 1.0139x over previous
//
#include <hip/hip_runtime.h>

// Fused 2-layer LSTM, bf16 MFMA recurrence, weights resident in VGPRs.
// 16 blocks x 512 threads; block b owns batches [16b, 16b+16).
// Per wave w (8 waves): gate-row tiles {q*8+w}, q=0..3 => i/f/g/o rows of
// h-columns [w*16, w*16+16) -> elementwise is lane-local on MFMA D-frags.
// R2: VALU diet — exp2 builtin, cvt_pk_bf16 packing, bias folded into
// MFMA (k=12 const-1 column for L0, C-init regs for L1), unroll-2 so the
// double-buffer parity is compile-time.

typedef short bf16x8 __attribute__((ext_vector_type(8)));
typedef float f32x4 __attribute__((ext_vector_type(4)));

static constexpr int CIN = 12, T = 2048, H = 128;
static constexpr int BPB = 16, NTHR = 512, NBLK = 16;
static constexpr float L2E = 1.4426950408889634f;

// LDS byte map
static constexpr int LDS_H0  = 0;      // 2 x 4096  (h0 double buffer, B-frag layout)
static constexpr int LDS_H1  = 8192;   // 2 x 4096  (h1 double buffer)
static constexpr int LDS_X   = 16384;  // 2 x 1024  (x_t, k=12 col == 1.0 -> L0 bias)
static constexpr int LDS_RED = 18432;  // 512 f32 reduction scratch (epilogue)
static constexpr int LDS_SZ  = 20480;

#if __has_builtin(__builtin_amdgcn_exp2f)
#define EXP2(x) __builtin_amdgcn_exp2f(x)
#else
#define EXP2(x) exp2f(x)
#endif

__device__ __forceinline__ unsigned f2bf(float f) {  // f32 -> bf16 bits, RTNE (prologue only)
  unsigned u = __builtin_bit_cast(unsigned, f);
  return (u + 0x7FFFu + ((u >> 16) & 1u)) >> 16;
}

__device__ __forceinline__ unsigned cvtpk_bf16(float lo, float hi) {
  unsigned r;
  asm("v_cvt_pk_bf16_f32 %0, %1, %2" : "=v"(r) : "v"(lo), "v"(hi));
  return r;
}

__device__ __forceinline__ float sig_pre(float a) {  // 1/(1+2^a)
  return __builtin_amdgcn_rcpf(1.f + EXP2(a));
}

__global__ __launch_bounds__(NTHR, 2) void lstm_fused(
    const float* __restrict__ xg,
    const float* __restrict__ Wih0, const float* __restrict__ Whh0,
    const float* __restrict__ bih0, const float* __restrict__ bhh0,
    const float* __restrict__ Wih1, const float* __restrict__ Whh1,
    const float* __restrict__ bih1, const float* __restrict__ bhh1,
    const float* __restrict__ Wd,   const float* __restrict__ bd,
    float* __restrict__ out)
{
  __shared__ char lds[LDS_SZ];
  const int tid = threadIdx.x;
  const int l  = tid & 63;
  const int w  = tid >> 6;   // wave 0..7
  const int lg = l >> 4;     // lane group 0..3 (k-chunk)
  const int lr = l & 15;     // A: row-in-tile ; B/D: batch column
  const int b0 = blockIdx.x * BPB;

  // ---- zero LDS (x pad region + initial h0/h1 state = 0) ----
  for (int i = tid; i < LDS_SZ / 4; i += NTHR) ((int*)lds)[i] = 0;
  __syncthreads();
  // constant-1.0 column at k==12 of both X buffers (feeds L0 bias row in A)
  if (tid < 32) {
    const int buf = tid >> 4, b = tid & 15;
    *(unsigned short*)(lds + LDS_X + buf * 1024 + 256 + b * 16 + 8) = 0x3F80;
  }

  // ---- load weight A-fragments (pre-scaled: i,f,o rows *-log2e ; g rows *2log2e) ----
  bf16x8 A0[4][5];  // layer0: K = [h0(128) ; x(12) ; 1 ; pad] -> 5 kfrags
  bf16x8 A1[4][8];  // layer1: K = [h1(128) ; h0(128)]        -> 8 kfrags
  f32x4 b1r[4];     // layer1 bias as MFMA C-init (D-frag layout: row = lg*4+r)
  #pragma unroll
  for (int q = 0; q < 4; ++q) {
    const int n = (q * 8 + w) * 16 + lr;         // global gate row 0..511
    const float s = (q == 2) ? (2.f * L2E) : (-L2E);
    #pragma unroll
    for (int kf = 0; kf < 4; ++kf) {
      const float* src = &Whh0[n * H + kf * 32 + lg * 8];
      #pragma unroll
      for (int j = 0; j < 8; ++j) A0[q][kf][j] = (short)f2bf(src[j] * s);
    }
    #pragma unroll
    for (int j = 0; j < 8; ++j) {
      const int k = lg * 8 + j;
      float v = 0.f;
      if (k < CIN) v = Wih0[n * CIN + k] * s;
      else if (k == CIN) v = (bih0[n] + bhh0[n]) * s;   // bias column, pairs with 1.0 in X
      A0[q][4][j] = (short)f2bf(v);
    }
    #pragma unroll
    for (int kf = 0; kf < 4; ++kf) {
      const float* srcA = &Whh1[n * H + kf * 32 + lg * 8];
      const float* srcB = &Wih1[n * H + kf * 32 + lg * 8];
      #pragma unroll
      for (int j = 0; j < 8; ++j) {
        A1[q][kf][j]     = (short)f2bf(srcA[j] * s);
        A1[q][4 + kf][j] = (short)f2bf(srcB[j] * s);
      }
    }
    #pragma unroll
    for (int r = 0; r < 4; ++r) {
      const int nd = (q * 8 + w) * 16 + lg * 4 + r;  // D-frag row for this lane
      b1r[q][r] = (bih1[nd] + bhh1[nd]) * s;
    }
  }
  const f32x4 zed = {0.f, 0.f, 0.f, 0.f};

  // per-lane LDS addresses
  const int rdB  = lg * 256 + lr * 16;                       // B-frag read base
  const int bcol = w * 16 + lg * 4;                          // base h-column (4 per lane)
  const int wrH  = (bcol >> 3) * 256 + lr * 16 + (bcol & 7) * 2;
  const int xb = tid & 15, xc = tid >> 4;                    // x loader role (tid<192)
  const int wrX = (xc >> 3) * 256 + xb * 16 + (xc & 7) * 2;
  const size_t xbase = (size_t)(b0 + xb) * (CIN * T) + (size_t)xc * T;

  // x(t=0) into X[0]
  if (tid < 192)
    *(unsigned short*)(lds + LDS_X + wrX) = (unsigned short)f2bf(xg[xbase]);
  __syncthreads();

  float c0v[4] = {0.f, 0.f, 0.f, 0.f};
  float c1v[4] = {0.f, 0.f, 0.f, 0.f};
  float h1v[4] = {0.f, 0.f, 0.f, 0.f};

  #pragma unroll 2
  for (int t = 0; t < T; ++t) {
    const int p = t & 1;
    // prefetch x(t+1) (consumed late in this iteration)
    float xnext = 0.f;
    if (tid < 192) xnext = xg[xbase + (t + 1 < T ? t + 1 : t)];

    // ================= layer 0 =================
    f32x4 acc[4];
    #pragma unroll
    for (int q = 0; q < 4; ++q) acc[q] = zed;
    #pragma unroll
    for (int kf = 0; kf < 5; ++kf) {
      const int src = (kf < 4) ? (LDS_H0 + p * 4096 + kf * 1024 + rdB)
                               : (LDS_X + p * 1024 + rdB);
      const bf16x8 bf = *(const bf16x8*)(lds + src);
      #pragma unroll
      for (int q = 0; q < 4; ++q)
        acc[q] = __builtin_amdgcn_mfma_f32_16x16x32_bf16(A0[q][kf], bf, acc[q], 0, 0, 0);
    }
    {
      float h0t[4];
      #pragma unroll
      for (int r = 0; r < 4; ++r) {
        const float iv = sig_pre(acc[0][r]);
        const float fv = sig_pre(acc[1][r]);
        const float gv = fmaf(-2.f, sig_pre(acc[2][r]), 1.f);
        const float ov = sig_pre(acc[3][r]);
        const float c  = fmaf(fv, c0v[r], iv * gv);
        c0v[r] = c;
        const float th = fmaf(-2.f, sig_pre(c * (2.f * L2E)), 1.f);
        h0t[r] = ov * th;
      }
      const unsigned hp0 = cvtpk_bf16(h0t[0], h0t[1]);
      const unsigned hp1 = cvtpk_bf16(h0t[2], h0t[3]);
      const unsigned long long hv64 = ((unsigned long long)hp1 << 32) | hp0;
      *(unsigned long long*)(lds + LDS_H0 + (1 - p) * 4096 + wrH) = hv64;
    }
    if (tid < 192) {
      const unsigned xp = cvtpk_bf16(xnext, xnext);
      *(unsigned short*)(lds + LDS_X + (1 - p) * 1024 + wrX) = (unsigned short)xp;
    }
    __syncthreads();

    // ================= layer 1 =================
    #pragma unroll
    for (int q = 0; q < 4; ++q) acc[q] = b1r[q];
    #pragma unroll
    for (int kf = 0; kf < 8; ++kf) {
      const int src = (kf < 4)
          ? (LDS_H1 + p * 4096 + kf * 1024 + rdB)
          : (LDS_H0 + (1 - p) * 4096 + (kf - 4) * 1024 + rdB);  // h0(t) just written
      const bf16x8 bf = *(const bf16x8*)(lds + src);
      #pragma unroll
      for (int q = 0; q < 4; ++q)
        acc[q] = __builtin_amdgcn_mfma_f32_16x16x32_bf16(A1[q][kf], bf, acc[q], 0, 0, 0);
    }
    {
      #pragma unroll
      for (int r = 0; r < 4; ++r) {
        const float iv = sig_pre(acc[0][r]);
        const float fv = sig_pre(acc[1][r]);
        const float gv = fmaf(-2.f, sig_pre(acc[2][r]), 1.f);
        const float ov = sig_pre(acc[3][r]);
        const float c  = fmaf(fv, c1v[r], iv * gv);
        c1v[r] = c;
        const float th = fmaf(-2.f, sig_pre(c * (2.f * L2E)), 1.f);
        h1v[r] = ov * th;
      }
      const unsigned hp0 = cvtpk_bf16(h1v[0], h1v[1]);
      const unsigned hp1 = cvtpk_bf16(h1v[2], h1v[3]);
      const unsigned long long hv64 = ((unsigned long long)hp1 << 32) | hp0;
      *(unsigned long long*)(lds + LDS_H1 + (1 - p) * 4096 + wrH) = hv64;
    }
    __syncthreads();
  }

  // ---- epilogue: feats = h1(T-1) (f32 from regs), scores = sigmoid(h1.Wd + bd) ----
  const float4 wd = *(const float4*)&Wd[bcol];
  const float partial = h1v[0] * wd.x + h1v[1] * wd.y + h1v[2] * wd.z + h1v[3] * wd.w;
  #pragma unroll
  for (int r = 0; r < 4; ++r)
    out[256 + (size_t)(b0 + lr) * H + (bcol + r)] = h1v[r];
  ((float*)(lds + LDS_RED))[tid] = partial;
  __syncthreads();
  if (tid < 16) {
    float s = 0.f;
    #pragma unroll 8
    for (int k = 0; k < 32; ++k) s += ((float*)(lds + LDS_RED))[tid + 16 * k];
    const float v = s + bd[0];
    out[b0 + tid] = __builtin_amdgcn_rcpf(1.f + EXP2(-v * L2E));
  }
}

extern "C" void kernel_launch(void* const* d_in, const int* in_sizes, int n_in,
                              void* d_out, int out_size, void* d_ws, size_t ws_size,
                              hipStream_t stream) {
  const float* x    = (const float*)d_in[0];
  // d_in[1] = seq_lengths : unused by the reference
  const float* Wih0 = (const float*)d_in[2];
  const float* Whh0 = (const float*)d_in[3];
  const float* bih0 = (const float*)d_in[4];
  const float* bhh0 = (const float*)d_in[5];
  const float* Wih1 = (const float*)d_in[6];
  const float* Whh1 = (const float*)d_in[7];
  const float* bih1 = (const float*)d_in[8];
  const float* bhh1 = (const float*)d_in[9];
  const float* Wd   = (const float*)d_in[10];
  const float* bd   = (const float*)d_in[11];
  (void)in_sizes; (void)n_in; (void)out_size; (void)d_ws; (void)ws_size;

  lstm_fused<<<dim3(NBLK), dim3(NTHR), 0, stream>>>(
      x, Wih0, Whh0, bih0, bhh0, Wih1, Whh1, bih1, bhh1, Wd, bd, (float*)d_out);
}